// Round 10
// baseline (93.543 us; speedup 1.0000x reference)
//
#include <hip/hip_runtime.h>
#include <cstdint>
#include <cstddef>

#define NN 8192
#define INF 512
#define OUTF 64
#define ALPHA 0.2f
#define NSPLIT 16
#define JSPLIT (NN / NSPLIT)   // 512
#define NW32 (NN / 32)         // 256 mask words per row
#define GEMM_BLOCKS 512

typedef short bf16x8 __attribute__((ext_vector_type(8)));
typedef float f32x4 __attribute__((ext_vector_type(4)));

static __device__ inline unsigned short f2bf(float f) {
    unsigned u = __builtin_bit_cast(unsigned, f);
    unsigned r = (u + 0x7FFFu + ((u >> 16) & 1u)) >> 16;
    return (unsigned short)r;
}

// ---------------------------------------------------------------------------
// Kernel 01 (fused): blocks 0..511 = GEMM (LDS-free, scalar-x), blocks
// 512..8703 = adj->bitmask pack (proven round-5 structure). GEMM epilogue
// writes the FACTORED exp vectors (U=exp(.8 s1), E2p=exp(s2), E2n=exp(.2 s2))
// so k2's 67M-score loop has zero transcendentals. Row factor exp(.2 s1)
// cancels in softmax.
// ---------------------------------------------------------------------------
__global__ __launch_bounds__(256) void k01_fused(
    const float* __restrict__ x, const int* __restrict__ adj,
    const float* __restrict__ W, const float* __restrict__ a,
    unsigned short* __restrict__ Asw, float* __restrict__ U,
    float* __restrict__ E2p, float* __restrict__ E2n,
    unsigned* __restrict__ mask)
{
    __shared__ int ldsbuf[8192];   // 32 KB (mask path only)
    const int tid = threadIdx.x;

    if (blockIdx.x >= GEMM_BLOCKS) {
        const int row = blockIdx.x - GEMM_BLOCKS;
        const int* arow = adj + (size_t)row * NN;

        #pragma unroll
        for (int k = 0; k < 8; ++k) {
            const int i = k * 1024 + tid * 4;
            int4 v = *(const int4*)(arow + i);
            const int p = i ^ (((i >> 7) & 7) << 2);
            *(int4*)&ldsbuf[p] = v;
        }
        __syncthreads();

        unsigned m = 0;
        #pragma unroll
        for (int k = 0; k < 8; ++k) {
            const int i2 = tid * 32 + k * 4;
            const int p2 = i2 ^ (((i2 >> 7) & 7) << 2);
            int4 v = *(const int4*)&ldsbuf[p2];
            m |= (v.x != 0 ? 1u : 0u) << (4 * k);
            m |= (v.y != 0 ? 1u : 0u) << (4 * k + 1);
            m |= (v.z != 0 ? 1u : 0u) << (4 * k + 2);
            m |= (v.w != 0 ? 1u : 0u) << (4 * k + 3);
        }
        mask[(size_t)row * NW32 + tid] = m;
        return;
    }

    const int i0 = blockIdx.x * 16;
    const int w  = __builtin_amdgcn_readfirstlane(tid >> 6);
    const int c  = tid & 63;

    const float* xr = x + (size_t)(i0 + 4 * w) * INF;
    const float* Wc = W + c;
    float acc[4] = {0.f, 0.f, 0.f, 0.f};

    #pragma unroll 4
    for (int kk = 0; kk < 128; ++kk) {
        const float4 x0 = *(const float4*)(xr + 0 * INF + kk * 4);
        const float4 x1 = *(const float4*)(xr + 1 * INF + kk * 4);
        const float4 x2 = *(const float4*)(xr + 2 * INF + kk * 4);
        const float4 x3 = *(const float4*)(xr + 3 * INF + kk * 4);
        const float w0 = Wc[(kk * 4 + 0) * OUTF];
        const float w1 = Wc[(kk * 4 + 1) * OUTF];
        const float w2 = Wc[(kk * 4 + 2) * OUTF];
        const float w3 = Wc[(kk * 4 + 3) * OUTF];
        acc[0] = fmaf(x0.x, w0, fmaf(x0.y, w1, fmaf(x0.z, w2, fmaf(x0.w, w3, acc[0]))));
        acc[1] = fmaf(x1.x, w0, fmaf(x1.y, w1, fmaf(x1.z, w2, fmaf(x1.w, w3, acc[1]))));
        acc[2] = fmaf(x2.x, w0, fmaf(x2.y, w1, fmaf(x2.z, w2, fmaf(x2.w, w3, acc[2]))));
        acc[3] = fmaf(x3.x, w0, fmaf(x3.y, w1, fmaf(x3.z, w2, fmaf(x3.w, w3, acc[3]))));
    }

    const float a1c = a[c];
    const float a2c = a[64 + c];
    #pragma unroll
    for (int q = 0; q < 4; ++q) {
        float v1 = acc[q] * a1c;
        float v2 = acc[q] * a2c;
        #pragma unroll
        for (int m = 32; m; m >>= 1) {
            v1 += __shfl_xor(v1, m, 64);
            v2 += __shfl_xor(v2, m, 64);
        }
        if (c == 0) {
            const int i = i0 + 4 * w + q;
            U[i]   = __expf((1.0f - ALPHA) * v1);   // exp(0.8 s1)
            E2p[i] = __expf(v2);                    // exp(s2)
            E2n[i] = __expf(ALPHA * v2);            // exp(0.2 s2)
        }
    }

    const int i   = i0 + 4 * w;
    const int jt  = i >> 5;
    const int sub = (i >> 3) & 3;
    const int e0  = i & 7;
    ushort4 pk;
    pk.x = f2bf(acc[0]); pk.y = f2bf(acc[1]);
    pk.z = f2bf(acc[2]); pk.w = f2bf(acc[3]);
    *(ushort4*)&Asw[((size_t)(c >> 4) * 256 + jt) * 512 + ((c & 15) + 16 * sub) * 8 + e0] = pk;
}

// ---------------------------------------------------------------------------
// Kernel 2: round-9 body byte-for-byte; ONLY the task map changed:
//   block = 4 consecutive i-tiles x ONE shared split (split = bid>>6).
//   A-fragments depend only on (split, t, l) -> identical across the block's
//   4 waves -> 3 of 4 A-loads are L1 hits; per-CU L2 demand drops 4x.
// ---------------------------------------------------------------------------
__global__ __launch_bounds__(256) void k2_attn(
    const unsigned* __restrict__ mask, const unsigned short* __restrict__ Asw,
    const float* __restrict__ Ug, const float* __restrict__ E2pg,
    const float* __restrict__ E2ng,
    float* __restrict__ Opart, float* __restrict__ lpart)
{
    const int l     = threadIdx.x & 63;
    const int w     = threadIdx.x >> 6;
    const int split = blockIdx.x >> 6;              // 64 blocks per split
    const int it    = (blockIdx.x & 63) * 4 + w;    // wave-private i-tile
    const int i0    = it * 32;
    const int jbase = split * JSPLIT;
    const int jb32  = jbase >> 5;

    const int il  = l & 15;
    const int kg  = l >> 4;
    const int kg8 = kg * 8;

    const float ua = Ug[i0 + il];
    const float ub = Ug[i0 + 16 + il];

    const unsigned* mbase = mask + (size_t)(i0 + il) * NW32 + jb32 + kg;
    unsigned mA[4], mB[4];
    #pragma unroll
    for (int ss = 0; ss < 4; ++ss) {
        mA[ss] = mbase[ss * 4];
        mB[ss] = mbase[(size_t)16 * NW32 + ss * 4];
    }

    f32x4 a00 = {0,0,0,0}, a01 = {0,0,0,0}, a10 = {0,0,0,0}, a11 = {0,0,0,0};
    f32x4 a20 = {0,0,0,0}, a21 = {0,0,0,0}, a30 = {0,0,0,0}, a31 = {0,0,0,0};
    float rsA = 0.f, rsB = 0.f;

    const unsigned short* A8 = Asw + (size_t)jb32 * 512 + l * 8;
    const float* ep0 = E2pg + jbase + kg8;
    const float* en0 = E2ng + jbase + kg8;

    bf16x8 A0c = *(const bf16x8*)(A8);
    bf16x8 A1c = *(const bf16x8*)(A8 + 131072);
    bf16x8 A2c = *(const bf16x8*)(A8 + 262144);
    bf16x8 A3c = *(const bf16x8*)(A8 + 393216);
    float4 pc0 = *(const float4*)(ep0);
    float4 pc1 = *(const float4*)(ep0 + 4);
    float4 nc0 = *(const float4*)(en0);
    float4 nc1 = *(const float4*)(en0 + 4);
    unsigned bAc = (__shfl(mA[0], il, 64) >> kg8) & 0xffu;
    unsigned bBc = (__shfl(mB[0], il, 64) >> kg8) & 0xffu;

#define SCM(UU, EP, EN, BITS, K)                                              \
    ((((BITS) >> (K)) & 1u) ? fmaxf((UU) * (EP), (EN)) : 0.f)

    #pragma unroll
    for (int t = 0; t < 16; ++t) {
        // ---- prefetch step t+1 (last step reloads itself; harmless) ----
        const int tn = (t < 15) ? t + 1 : t;
        const unsigned short* An = Asw + (size_t)(jb32 + tn) * 512 + l * 8;
        bf16x8 A0n = *(const bf16x8*)(An);
        bf16x8 A1n = *(const bf16x8*)(An + 131072);
        bf16x8 A2n = *(const bf16x8*)(An + 262144);
        bf16x8 A3n = *(const bf16x8*)(An + 393216);
        const float* epn = E2pg + jbase + tn * 32 + kg8;
        const float* enn = E2ng + jbase + tn * 32 + kg8;
        float4 pn0 = *(const float4*)(epn);
        float4 pn1 = *(const float4*)(epn + 4);
        float4 nn0 = *(const float4*)(enn);
        float4 nn1 = *(const float4*)(enn + 4);
        const int ssn = tn >> 2, ksn = tn & 3;
        unsigned bAn = (__shfl(mA[ssn], il + 16 * ksn, 64) >> kg8) & 0xffu;
        unsigned bBn = (__shfl(mB[ssn], il + 16 * ksn, 64) >> kg8) & 0xffu;

        // ---- compute step t: 5 VALU/score, no transcendentals ----
        const float p0 = SCM(ua, pc0.x, nc0.x, bAc, 0);
        const float p1 = SCM(ua, pc0.y, nc0.y, bAc, 1);
        const float p2 = SCM(ua, pc0.z, nc0.z, bAc, 2);
        const float p3 = SCM(ua, pc0.w, nc0.w, bAc, 3);
        const float p4 = SCM(ua, pc1.x, nc1.x, bAc, 4);
        const float p5 = SCM(ua, pc1.y, nc1.y, bAc, 5);
        const float p6 = SCM(ua, pc1.z, nc1.z, bAc, 6);
        const float p7 = SCM(ua, pc1.w, nc1.w, bAc, 7);
        const float q0 = SCM(ub, pc0.x, nc0.x, bBc, 0);
        const float q1 = SCM(ub, pc0.y, nc0.y, bBc, 1);
        const float q2 = SCM(ub, pc0.z, nc0.z, bBc, 2);
        const float q3 = SCM(ub, pc0.w, nc0.w, bBc, 3);
        const float q4 = SCM(ub, pc1.x, nc1.x, bBc, 4);
        const float q5 = SCM(ub, pc1.y, nc1.y, bBc, 5);
        const float q6 = SCM(ub, pc1.z, nc1.z, bBc, 6);
        const float q7 = SCM(ub, pc1.w, nc1.w, bBc, 7);

        rsA += ((p0 + p1) + (p2 + p3)) + ((p4 + p5) + (p6 + p7));
        rsB += ((q0 + q1) + (q2 + q3)) + ((q4 + q5) + (q6 + q7));

        uint4 wa, wb;
        asm("v_cvt_pk_bf16_f32 %0, %1, %2" : "=v"(wa.x) : "v"(p0), "v"(p1));
        asm("v_cvt_pk_bf16_f32 %0, %1, %2" : "=v"(wa.y) : "v"(p2), "v"(p3));
        asm("v_cvt_pk_bf16_f32 %0, %1, %2" : "=v"(wa.z) : "v"(p4), "v"(p5));
        asm("v_cvt_pk_bf16_f32 %0, %1, %2" : "=v"(wa.w) : "v"(p6), "v"(p7));
        asm("v_cvt_pk_bf16_f32 %0, %1, %2" : "=v"(wb.x) : "v"(q0), "v"(q1));
        asm("v_cvt_pk_bf16_f32 %0, %1, %2" : "=v"(wb.y) : "v"(q2), "v"(q3));
        asm("v_cvt_pk_bf16_f32 %0, %1, %2" : "=v"(wb.z) : "v"(q4), "v"(q5));
        asm("v_cvt_pk_bf16_f32 %0, %1, %2" : "=v"(wb.w) : "v"(q6), "v"(q7));
        const bf16x8 BA = __builtin_bit_cast(bf16x8, wa);
        const bf16x8 BB = __builtin_bit_cast(bf16x8, wb);

        a00 = __builtin_amdgcn_mfma_f32_16x16x32_bf16(A0c, BA, a00, 0, 0, 0);
        a01 = __builtin_amdgcn_mfma_f32_16x16x32_bf16(A0c, BB, a01, 0, 0, 0);
        a10 = __builtin_amdgcn_mfma_f32_16x16x32_bf16(A1c, BA, a10, 0, 0, 0);
        a11 = __builtin_amdgcn_mfma_f32_16x16x32_bf16(A1c, BB, a11, 0, 0, 0);
        a20 = __builtin_amdgcn_mfma_f32_16x16x32_bf16(A2c, BA, a20, 0, 0, 0);
        a21 = __builtin_amdgcn_mfma_f32_16x16x32_bf16(A2c, BB, a21, 0, 0, 0);
        a30 = __builtin_amdgcn_mfma_f32_16x16x32_bf16(A3c, BA, a30, 0, 0, 0);
        a31 = __builtin_amdgcn_mfma_f32_16x16x32_bf16(A3c, BB, a31, 0, 0, 0);

        A0c = A0n; A1c = A1n; A2c = A2n; A3c = A3n;
        pc0 = pn0; pc1 = pn1; nc0 = nn0; nc1 = nn1;
        bAc = bAn; bBc = bBn;
    }
#undef SCM

    rsA += __shfl_xor(rsA, 16, 64);
    rsA += __shfl_xor(rsA, 32, 64);
    rsB += __shfl_xor(rsB, 16, 64);
    rsB += __shfl_xor(rsB, 32, 64);
    if (l < 16) {
        lpart[(size_t)split * NN + i0 + il]      = rsA;
        lpart[(size_t)split * NN + i0 + 16 + il] = rsB;
    }

    const int nn4 = kg * 4;
    float* OA = Opart + ((size_t)split * NN + i0 + il) * OUTF + nn4;
    float* OB = OA + (size_t)16 * OUTF;
    *(float4*)(OA)      = *(float4*)&a00;
    *(float4*)(OA + 16) = *(float4*)&a10;
    *(float4*)(OA + 32) = *(float4*)&a20;
    *(float4*)(OA + 48) = *(float4*)&a30;
    *(float4*)(OB)      = *(float4*)&a01;
    *(float4*)(OB + 16) = *(float4*)&a11;
    *(float4*)(OB + 32) = *(float4*)&a21;
    *(float4*)(OB + 48) = *(float4*)&a31;
}

// ---------------------------------------------------------------------------
// Kernel 3: combine the 16 j-split partials and normalize.
// ---------------------------------------------------------------------------
__global__ __launch_bounds__(256) void k3_combine(
    const float* __restrict__ Opart, const float* __restrict__ lpart,
    float* __restrict__ out)
{
    const int f4 = blockIdx.x * 256 + threadIdx.x;
    const int i  = f4 >> 4;

    float4 r = {0.f, 0.f, 0.f, 0.f};
    float  lsum = 0.f;
    #pragma unroll
    for (int s = 0; s < NSPLIT; ++s) {
        float4 o = *(const float4*)&Opart[(size_t)s * NN * OUTF + (size_t)f4 * 4];
        r.x += o.x; r.y += o.y; r.z += o.z; r.w += o.w;
        lsum += lpart[(size_t)s * NN + i];
    }
    float inv = 1.0f / lsum;
    r.x *= inv; r.y *= inv; r.z *= inv; r.w *= inv;
    *(float4*)&out[(size_t)f4 * 4] = r;
}

extern "C" void kernel_launch(void* const* d_in, const int* in_sizes, int n_in,
                              void* d_out, int out_size, void* d_ws, size_t ws_size,
                              hipStream_t stream) {
    const float* x   = (const float*)d_in[0];
    const int*   adj = (const int*)d_in[1];
    const float* W   = (const float*)d_in[2];
    const float* a   = (const float*)d_in[3];
    float* out = (float*)d_out;

    char* ws = (char*)d_ws;
    unsigned short* Asw = (unsigned short*)ws;                        // 1 MB
    float* U     = (float*)(ws + (1 << 20));                          // 32 KB
    float* E2p   = (float*)(ws + (1 << 20) + 32768);                  // 32 KB
    float* E2n   = (float*)(ws + (1 << 20) + 65536);                  // 32 KB
    float* lpart = (float*)(ws + (1 << 20) + 98304);                  // 512 KB
    unsigned* mask = (unsigned*)(ws + (1 << 20) + 98304 + 524288);    // 8 MB
    float* Opart = (float*)(ws + (1 << 20) + 98304 + 524288 + (8 << 20)); // 32 MB

    k01_fused<<<GEMM_BLOCKS + NN, 256, 0, stream>>>(x, adj, W, a, Asw,
                                                    U, E2p, E2n, mask);
    k2_attn<<<1024, 256, 0, stream>>>(mask, Asw, U, E2p, E2n, Opart, lpart);
    k3_combine<<<512, 256, 0, stream>>>(Opart, lpart, out);
}

// Round 11
// 91.506 us; speedup vs baseline: 1.0223x; 1.0223x over previous
//
#include <hip/hip_runtime.h>
#include <cstdint>
#include <cstddef>

#define NN 8192
#define INF 512
#define OUTF 64
#define ALPHA 0.2f
#define NSPLIT 16
#define JSPLIT (NN / NSPLIT)   // 512
#define NW32 (NN / 32)         // 256 mask words per row
#define GEMM_BLOCKS 512

typedef short bf16x8 __attribute__((ext_vector_type(8)));
typedef float f32x4 __attribute__((ext_vector_type(4)));

static __device__ inline unsigned short f2bf(float f) {
    unsigned u = __builtin_bit_cast(unsigned, f);
    unsigned r = (u + 0x7FFFu + ((u >> 16) & 1u)) >> 16;
    return (unsigned short)r;
}

// ---------------------------------------------------------------------------
// Kernel 01 (fused): blocks 0..511 = GEMM (LDS-free, scalar-x), blocks
// 512..8703 = adj->bitmask pack (proven round-5 structure). GEMM epilogue
// writes the FACTORED exp vectors (U=exp(.8 s1), E2p=exp(s2), E2n=exp(.2 s2))
// so k2's 67M-score loop has zero transcendentals. Row factor exp(.2 s1)
// cancels in softmax.
// ---------------------------------------------------------------------------
__global__ __launch_bounds__(256) void k01_fused(
    const float* __restrict__ x, const int* __restrict__ adj,
    const float* __restrict__ W, const float* __restrict__ a,
    unsigned short* __restrict__ Asw, float* __restrict__ U,
    float* __restrict__ E2p, float* __restrict__ E2n,
    unsigned* __restrict__ mask)
{
    __shared__ int ldsbuf[8192];   // 32 KB (mask path only)
    const int tid = threadIdx.x;

    if (blockIdx.x >= GEMM_BLOCKS) {
        const int row = blockIdx.x - GEMM_BLOCKS;
        const int* arow = adj + (size_t)row * NN;

        #pragma unroll
        for (int k = 0; k < 8; ++k) {
            const int i = k * 1024 + tid * 4;
            int4 v = *(const int4*)(arow + i);
            const int p = i ^ (((i >> 7) & 7) << 2);
            *(int4*)&ldsbuf[p] = v;
        }
        __syncthreads();

        unsigned m = 0;
        #pragma unroll
        for (int k = 0; k < 8; ++k) {
            const int i2 = tid * 32 + k * 4;
            const int p2 = i2 ^ (((i2 >> 7) & 7) << 2);
            int4 v = *(const int4*)&ldsbuf[p2];
            m |= (v.x != 0 ? 1u : 0u) << (4 * k);
            m |= (v.y != 0 ? 1u : 0u) << (4 * k + 1);
            m |= (v.z != 0 ? 1u : 0u) << (4 * k + 2);
            m |= (v.w != 0 ? 1u : 0u) << (4 * k + 3);
        }
        mask[(size_t)row * NW32 + tid] = m;
        return;
    }

    const int i0 = blockIdx.x * 16;
    const int w  = __builtin_amdgcn_readfirstlane(tid >> 6);
    const int c  = tid & 63;

    const float* xr = x + (size_t)(i0 + 4 * w) * INF;
    const float* Wc = W + c;
    float acc[4] = {0.f, 0.f, 0.f, 0.f};

    #pragma unroll 4
    for (int kk = 0; kk < 128; ++kk) {
        const float4 x0 = *(const float4*)(xr + 0 * INF + kk * 4);
        const float4 x1 = *(const float4*)(xr + 1 * INF + kk * 4);
        const float4 x2 = *(const float4*)(xr + 2 * INF + kk * 4);
        const float4 x3 = *(const float4*)(xr + 3 * INF + kk * 4);
        const float w0 = Wc[(kk * 4 + 0) * OUTF];
        const float w1 = Wc[(kk * 4 + 1) * OUTF];
        const float w2 = Wc[(kk * 4 + 2) * OUTF];
        const float w3 = Wc[(kk * 4 + 3) * OUTF];
        acc[0] = fmaf(x0.x, w0, fmaf(x0.y, w1, fmaf(x0.z, w2, fmaf(x0.w, w3, acc[0]))));
        acc[1] = fmaf(x1.x, w0, fmaf(x1.y, w1, fmaf(x1.z, w2, fmaf(x1.w, w3, acc[1]))));
        acc[2] = fmaf(x2.x, w0, fmaf(x2.y, w1, fmaf(x2.z, w2, fmaf(x2.w, w3, acc[2]))));
        acc[3] = fmaf(x3.x, w0, fmaf(x3.y, w1, fmaf(x3.z, w2, fmaf(x3.w, w3, acc[3]))));
    }

    const float a1c = a[c];
    const float a2c = a[64 + c];
    #pragma unroll
    for (int q = 0; q < 4; ++q) {
        float v1 = acc[q] * a1c;
        float v2 = acc[q] * a2c;
        #pragma unroll
        for (int m = 32; m; m >>= 1) {
            v1 += __shfl_xor(v1, m, 64);
            v2 += __shfl_xor(v2, m, 64);
        }
        if (c == 0) {
            const int i = i0 + 4 * w + q;
            U[i]   = __expf((1.0f - ALPHA) * v1);   // exp(0.8 s1)
            E2p[i] = __expf(v2);                    // exp(s2)
            E2n[i] = __expf(ALPHA * v2);            // exp(0.2 s2)
        }
    }

    const int i   = i0 + 4 * w;
    const int jt  = i >> 5;
    const int sub = (i >> 3) & 3;
    const int e0  = i & 7;
    ushort4 pk;
    pk.x = f2bf(acc[0]); pk.y = f2bf(acc[1]);
    pk.z = f2bf(acc[2]); pk.w = f2bf(acc[3]);
    *(ushort4*)&Asw[((size_t)(c >> 4) * 256 + jt) * 512 + ((c & 15) + 16 * sub) * 8 + e0] = pk;
}

// ---------------------------------------------------------------------------
// Kernel 2: round-9 measured structure (92.2 us total) with ONE change set:
//   occupancy package. A-fragments are loaded IN-STEP (top of step t, consumed
//   by MFMA at the bottom, score math in between covers the latency) instead
//   of ping-ponged -> -16 VGPR; __launch_bounds__(256,4) caps VGPR at 128 ->
//   4 waves/SIMD instead of 3 (probe showed VGPR=140, just over the cliff).
// ---------------------------------------------------------------------------
__global__ __launch_bounds__(256, 4) void k2_attn(
    const unsigned* __restrict__ mask, const unsigned short* __restrict__ Asw,
    const float* __restrict__ Ug, const float* __restrict__ E2pg,
    const float* __restrict__ E2ng,
    float* __restrict__ Opart, float* __restrict__ lpart)
{
    const int l    = threadIdx.x & 63;
    const int task = blockIdx.x * 4 + (threadIdx.x >> 6);

    const int it    = task >> 4;
    const int split = task & 15;
    const int i0    = it * 32;
    const int jbase = split * JSPLIT;
    const int jb32  = jbase >> 5;

    const int il  = l & 15;
    const int kg  = l >> 4;
    const int kg8 = kg * 8;

    const float ua = Ug[i0 + il];
    const float ub = Ug[i0 + 16 + il];

    const unsigned* mbase = mask + (size_t)(i0 + il) * NW32 + jb32 + kg;
    unsigned mA[4], mB[4];
    #pragma unroll
    for (int ss = 0; ss < 4; ++ss) {
        mA[ss] = mbase[ss * 4];
        mB[ss] = mbase[(size_t)16 * NW32 + ss * 4];
    }

    f32x4 a00 = {0,0,0,0}, a01 = {0,0,0,0}, a10 = {0,0,0,0}, a11 = {0,0,0,0};
    f32x4 a20 = {0,0,0,0}, a21 = {0,0,0,0}, a30 = {0,0,0,0}, a31 = {0,0,0,0};
    float rsA = 0.f, rsB = 0.f;

    const float* ep0 = E2pg + jbase + kg8;
    const float* en0 = E2ng + jbase + kg8;

    // E2/mask ping-pong only (they head the score dependence chain)
    float4 pc0 = *(const float4*)(ep0);
    float4 pc1 = *(const float4*)(ep0 + 4);
    float4 nc0 = *(const float4*)(en0);
    float4 nc1 = *(const float4*)(en0 + 4);
    unsigned bAc = (__shfl(mA[0], il, 64) >> kg8) & 0xffu;
    unsigned bBc = (__shfl(mB[0], il, 64) >> kg8) & 0xffu;

#define SCM(UU, EP, EN, BITS, K)                                              \
    ((((BITS) >> (K)) & 1u) ? fmaxf((UU) * (EP), (EN)) : 0.f)

    #pragma unroll
    for (int t = 0; t < 16; ++t) {
        // ---- A-fragments for THIS step: issued here, consumed after the
        //      score math below (no score->A dependency; ~150 cy cover) ----
        const unsigned short* Ac = Asw + (size_t)(jb32 + t) * 512 + l * 8;
        bf16x8 A0c = *(const bf16x8*)(Ac);
        bf16x8 A1c = *(const bf16x8*)(Ac + 131072);
        bf16x8 A2c = *(const bf16x8*)(Ac + 262144);
        bf16x8 A3c = *(const bf16x8*)(Ac + 393216);

        // ---- prefetch E2/mask for step t+1 ----
        const int tn = (t < 15) ? t + 1 : t;
        const float* epn = E2pg + jbase + tn * 32 + kg8;
        const float* enn = E2ng + jbase + tn * 32 + kg8;
        float4 pn0 = *(const float4*)(epn);
        float4 pn1 = *(const float4*)(epn + 4);
        float4 nn0 = *(const float4*)(enn);
        float4 nn1 = *(const float4*)(enn + 4);
        const int ssn = tn >> 2, ksn = tn & 3;
        unsigned bAn = (__shfl(mA[ssn], il + 16 * ksn, 64) >> kg8) & 0xffu;
        unsigned bBn = (__shfl(mB[ssn], il + 16 * ksn, 64) >> kg8) & 0xffu;

        // ---- score math for step t (5 VALU/score, no transcendentals) ----
        const float p0 = SCM(ua, pc0.x, nc0.x, bAc, 0);
        const float p1 = SCM(ua, pc0.y, nc0.y, bAc, 1);
        const float p2 = SCM(ua, pc0.z, nc0.z, bAc, 2);
        const float p3 = SCM(ua, pc0.w, nc0.w, bAc, 3);
        const float p4 = SCM(ua, pc1.x, nc1.x, bAc, 4);
        const float p5 = SCM(ua, pc1.y, nc1.y, bAc, 5);
        const float p6 = SCM(ua, pc1.z, nc1.z, bAc, 6);
        const float p7 = SCM(ua, pc1.w, nc1.w, bAc, 7);
        const float q0 = SCM(ub, pc0.x, nc0.x, bBc, 0);
        const float q1 = SCM(ub, pc0.y, nc0.y, bBc, 1);
        const float q2 = SCM(ub, pc0.z, nc0.z, bBc, 2);
        const float q3 = SCM(ub, pc0.w, nc0.w, bBc, 3);
        const float q4 = SCM(ub, pc1.x, nc1.x, bBc, 4);
        const float q5 = SCM(ub, pc1.y, nc1.y, bBc, 5);
        const float q6 = SCM(ub, pc1.z, nc1.z, bBc, 6);
        const float q7 = SCM(ub, pc1.w, nc1.w, bBc, 7);

        rsA += ((p0 + p1) + (p2 + p3)) + ((p4 + p5) + (p6 + p7));
        rsB += ((q0 + q1) + (q2 + q3)) + ((q4 + q5) + (q6 + q7));

        uint4 wa, wb;
        asm("v_cvt_pk_bf16_f32 %0, %1, %2" : "=v"(wa.x) : "v"(p0), "v"(p1));
        asm("v_cvt_pk_bf16_f32 %0, %1, %2" : "=v"(wa.y) : "v"(p2), "v"(p3));
        asm("v_cvt_pk_bf16_f32 %0, %1, %2" : "=v"(wa.z) : "v"(p4), "v"(p5));
        asm("v_cvt_pk_bf16_f32 %0, %1, %2" : "=v"(wa.w) : "v"(p6), "v"(p7));
        asm("v_cvt_pk_bf16_f32 %0, %1, %2" : "=v"(wb.x) : "v"(q0), "v"(q1));
        asm("v_cvt_pk_bf16_f32 %0, %1, %2" : "=v"(wb.y) : "v"(q2), "v"(q3));
        asm("v_cvt_pk_bf16_f32 %0, %1, %2" : "=v"(wb.z) : "v"(q4), "v"(q5));
        asm("v_cvt_pk_bf16_f32 %0, %1, %2" : "=v"(wb.w) : "v"(q6), "v"(q7));
        const bf16x8 BA = __builtin_bit_cast(bf16x8, wa);
        const bf16x8 BB = __builtin_bit_cast(bf16x8, wb);

        a00 = __builtin_amdgcn_mfma_f32_16x16x32_bf16(A0c, BA, a00, 0, 0, 0);
        a01 = __builtin_amdgcn_mfma_f32_16x16x32_bf16(A0c, BB, a01, 0, 0, 0);
        a10 = __builtin_amdgcn_mfma_f32_16x16x32_bf16(A1c, BA, a10, 0, 0, 0);
        a11 = __builtin_amdgcn_mfma_f32_16x16x32_bf16(A1c, BB, a11, 0, 0, 0);
        a20 = __builtin_amdgcn_mfma_f32_16x16x32_bf16(A2c, BA, a20, 0, 0, 0);
        a21 = __builtin_amdgcn_mfma_f32_16x16x32_bf16(A2c, BB, a21, 0, 0, 0);
        a30 = __builtin_amdgcn_mfma_f32_16x16x32_bf16(A3c, BA, a30, 0, 0, 0);
        a31 = __builtin_amdgcn_mfma_f32_16x16x32_bf16(A3c, BB, a31, 0, 0, 0);

        pc0 = pn0; pc1 = pn1; nc0 = nn0; nc1 = nn1;
        bAc = bAn; bBc = bBn;
    }
#undef SCM

    rsA += __shfl_xor(rsA, 16, 64);
    rsA += __shfl_xor(rsA, 32, 64);
    rsB += __shfl_xor(rsB, 16, 64);
    rsB += __shfl_xor(rsB, 32, 64);
    if (l < 16) {
        lpart[(size_t)split * NN + i0 + il]      = rsA;
        lpart[(size_t)split * NN + i0 + 16 + il] = rsB;
    }

    const int nn4 = kg * 4;
    float* OA = Opart + ((size_t)split * NN + i0 + il) * OUTF + nn4;
    float* OB = OA + (size_t)16 * OUTF;
    *(float4*)(OA)      = *(float4*)&a00;
    *(float4*)(OA + 16) = *(float4*)&a10;
    *(float4*)(OA + 32) = *(float4*)&a20;
    *(float4*)(OA + 48) = *(float4*)&a30;
    *(float4*)(OB)      = *(float4*)&a01;
    *(float4*)(OB + 16) = *(float4*)&a11;
    *(float4*)(OB + 32) = *(float4*)&a21;
    *(float4*)(OB + 48) = *(float4*)&a31;
}

// ---------------------------------------------------------------------------
// Kernel 3: combine the 16 j-split partials and normalize.
// ---------------------------------------------------------------------------
__global__ __launch_bounds__(256) void k3_combine(
    const float* __restrict__ Opart, const float* __restrict__ lpart,
    float* __restrict__ out)
{
    const int f4 = blockIdx.x * 256 + threadIdx.x;
    const int i  = f4 >> 4;

    float4 r = {0.f, 0.f, 0.f, 0.f};
    float  lsum = 0.f;
    #pragma unroll
    for (int s = 0; s < NSPLIT; ++s) {
        float4 o = *(const float4*)&Opart[(size_t)s * NN * OUTF + (size_t)f4 * 4];
        r.x += o.x; r.y += o.y; r.z += o.z; r.w += o.w;
        lsum += lpart[(size_t)s * NN + i];
    }
    float inv = 1.0f / lsum;
    r.x *= inv; r.y *= inv; r.z *= inv; r.w *= inv;
    *(float4*)&out[(size_t)f4 * 4] = r;
}

extern "C" void kernel_launch(void* const* d_in, const int* in_sizes, int n_in,
                              void* d_out, int out_size, void* d_ws, size_t ws_size,
                              hipStream_t stream) {
    const float* x   = (const float*)d_in[0];
    const int*   adj = (const int*)d_in[1];
    const float* W   = (const float*)d_in[2];
    const float* a   = (const float*)d_in[3];
    float* out = (float*)d_out;

    char* ws = (char*)d_ws;
    unsigned short* Asw = (unsigned short*)ws;                        // 1 MB
    float* U     = (float*)(ws + (1 << 20));                          // 32 KB
    float* E2p   = (float*)(ws + (1 << 20) + 32768);                  // 32 KB
    float* E2n   = (float*)(ws + (1 << 20) + 65536);                  // 32 KB
    float* lpart = (float*)(ws + (1 << 20) + 98304);                  // 512 KB
    unsigned* mask = (unsigned*)(ws + (1 << 20) + 98304 + 524288);    // 8 MB
    float* Opart = (float*)(ws + (1 << 20) + 98304 + 524288 + (8 << 20)); // 32 MB

    k01_fused<<<GEMM_BLOCKS + NN, 256, 0, stream>>>(x, adj, W, a, Asw,
                                                    U, E2p, E2n, mask);
    k2_attn<<<1024, 256, 0, stream>>>(mask, Asw, U, E2p, E2n, Opart, lpart);
    k3_combine<<<512, 256, 0, stream>>>(Opart, lpart, out);
}